// Round 2
// 4797.306 us; speedup vs baseline: 1.5623x; 1.5623x over previous
//
#include <hip/hip_runtime.h>

// ---------------- problem constants ----------------
#define BB   32
#define SS   512
#define DD   256
#define HH   8
#define HDIM 64
#define NLAYER 5
#define FFD  1024
#define OUTD 4096
#define QN   512            // H*HD
#define BS   (BB*SS)        // 16384 tokens

// ---------------- embedding + positional encoding ----------------
__global__ __launch_bounds__(256) void embed_pe_kernel(
        const int* __restrict__ x, const float* __restrict__ emb,
        float* __restrict__ h) {
    int t = blockIdx.x;
    int d = threadIdx.x;
    int pos = t % SS;
    int tok = x[t];
    float e = emb[(size_t)tok * DD + d];
    float expo = -(float)(d & ~1) / (float)DD;
    float ang = (float)pos * powf(10000.0f, expo);
    float pe = (d & 1) ? cosf(ang) : sinf(ang);
    h[(size_t)t * DD + d] = e + pe;
}

// ---------------- generic tiled GEMM (f32 SIMT) ----------------
template<bool RELU>
__global__ __launch_bounds__(256) void gemm64_kernel(
        const float* __restrict__ A, const float* __restrict__ W,
        const float* __restrict__ bias, float* __restrict__ C,
        int M, int N, int K) {
    __shared__ float sA[16][65];
    __shared__ float sB[16][68];

    const int tid = threadIdx.x;
    const int tx = tid & 15;
    const int ty = tid >> 4;
    const int m0 = blockIdx.y * 64;
    const int n0 = blockIdx.x * 64;

    const int lam = tid >> 2;
    const int lak = (tid & 3) << 2;
    const int lwk = tid >> 4;
    const int lwn = (tid & 15) << 2;

    float acc[4][4];
#pragma unroll
    for (int i = 0; i < 4; ++i)
#pragma unroll
        for (int j = 0; j < 4; ++j) acc[i][j] = 0.0f;

    for (int k0 = 0; k0 < K; k0 += 16) {
        const float4 av = *reinterpret_cast<const float4*>(
            A + (size_t)(m0 + lam) * K + k0 + lak);
        sA[lak + 0][lam] = av.x;
        sA[lak + 1][lam] = av.y;
        sA[lak + 2][lam] = av.z;
        sA[lak + 3][lam] = av.w;
        const float4 wv = *reinterpret_cast<const float4*>(
            W + (size_t)(k0 + lwk) * N + n0 + lwn);
        sB[lwk][lwn + 0] = wv.x;
        sB[lwk][lwn + 1] = wv.y;
        sB[lwk][lwn + 2] = wv.z;
        sB[lwk][lwn + 3] = wv.w;
        __syncthreads();
#pragma unroll
        for (int k = 0; k < 16; ++k) {
            float a0 = sA[k][ty * 4 + 0];
            float a1 = sA[k][ty * 4 + 1];
            float a2 = sA[k][ty * 4 + 2];
            float a3 = sA[k][ty * 4 + 3];
            float b0 = sB[k][tx * 4 + 0];
            float b1 = sB[k][tx * 4 + 1];
            float b2 = sB[k][tx * 4 + 2];
            float b3 = sB[k][tx * 4 + 3];
            acc[0][0] += a0 * b0; acc[0][1] += a0 * b1; acc[0][2] += a0 * b2; acc[0][3] += a0 * b3;
            acc[1][0] += a1 * b0; acc[1][1] += a1 * b1; acc[1][2] += a1 * b2; acc[1][3] += a1 * b3;
            acc[2][0] += a2 * b0; acc[2][1] += a2 * b1; acc[2][2] += a2 * b2; acc[2][3] += a2 * b3;
            acc[3][0] += a3 * b0; acc[3][1] += a3 * b1; acc[3][2] += a3 * b2; acc[3][3] += a3 * b3;
        }
        __syncthreads();
    }

#pragma unroll
    for (int j = 0; j < 4; ++j) {
        int col = n0 + tx * 4 + j;
        float bv = bias[col];
#pragma unroll
        for (int i = 0; i < 4; ++i) {
            int row = m0 + ty * 4 + i;
            float v = acc[i][j] + bv;
            if (RELU) v = fmaxf(v, 0.0f);
            C[(size_t)row * N + col] = v;
        }
    }
}

// ---------------- flash attention (v2) ----------------
// One block per (q-tile of 64, head, batch). q,k,v,o: [BS, QN], col = h*64+d.
// o aliases q safely: each block reads only its own Q tile (staged first) and
// writes only that same region.
//
// v2 changes vs v1:
//  - softmax fully in registers: each 16-lane group owns 4 rows; row max/sum
//    via __shfl_xor over masks 1,2,4,8 (was: serial 64-thread scan, 3/4 waves idle)
//  - P is stored into the Ks buffer (K dead after S) -> LDS 69KB -> 48KB,
//    2 -> 3 blocks/CU
//  - XOR swizzle on the float4-granule index, stride 64:
//    addr(row,c4) = row*64 + ((c4 ^ (row>>2))<<2).  K-reads (rows tx*4+j)
//    land on 16 distinct granules (2-way banks, free); Q/P reads broadcast
//    conflict-free; V stays linear (reads are row-broadcast/contiguous).
__global__ __launch_bounds__(256) void flash_attn_kernel(
        const float* __restrict__ q, const float* __restrict__ k,
        const float* __restrict__ v, float* __restrict__ o) {
    const int qt  = blockIdx.x;   // 0..7
    const int hh  = blockIdx.y;   // 0..7
    const int b   = blockIdx.z;   // 0..31
    const int tid = threadIdx.x;
    const int tx  = tid & 15;     // score-col / out-col group
    const int ty  = tid >> 4;     // row group 0..15

    __shared__ float Qs[64][64];
    __shared__ float Ks[64][64];  // holds K during QK^T, then P during PV
    __shared__ float Vs[64][64];

    const size_t qbase = ((size_t)(b * SS + qt * 64)) * QN + hh * HDIM;

    // load Q tile (64x64), pre-scaled by 1/sqrt(HD)=0.125, swizzled
#pragma unroll
    for (int it = 0; it < 4; ++it) {
        int idx = tid + it * 256;          // 0..1023
        int row = idx >> 4, c4 = idx & 15;
        float4 qv = *reinterpret_cast<const float4*>(
            q + qbase + (size_t)row * QN + c4 * 4);
        float4 sq = make_float4(qv.x * 0.125f, qv.y * 0.125f,
                                qv.z * 0.125f, qv.w * 0.125f);
        *reinterpret_cast<float4*>(&Qs[row][(c4 ^ (row >> 2)) << 2]) = sq;
    }

    float o_acc[4][4];
    float m_i[4], l_i[4];
#pragma unroll
    for (int i = 0; i < 4; ++i) {
        m_i[i] = -3.4e38f;
        l_i[i] = 0.0f;
#pragma unroll
        for (int j = 0; j < 4; ++j) o_acc[i][j] = 0.0f;
    }

    for (int kt = 0; kt <= qt; ++kt) {
        __syncthreads();   // prev tile's Ks(P)/Vs fully consumed (also gates Qs at kt=0)
        const size_t kbase = ((size_t)(b * SS + kt * 64)) * QN + hh * HDIM;
#pragma unroll
        for (int it = 0; it < 4; ++it) {
            int idx = tid + it * 256;
            int row = idx >> 4, c4 = idx & 15;
            float4 kv = *reinterpret_cast<const float4*>(
                k + kbase + (size_t)row * QN + c4 * 4);
            *reinterpret_cast<float4*>(&Ks[row][(c4 ^ (row >> 2)) << 2]) = kv;
            float4 vv = *reinterpret_cast<const float4*>(
                v + kbase + (size_t)row * QN + c4 * 4);
            *reinterpret_cast<float4*>(&Vs[row][c4 << 2]) = vv;
        }
        __syncthreads();

        // S = Q·K^T : thread computes rows ty*4.., score-cols tx*4..
        float s[4][4];
#pragma unroll
        for (int i = 0; i < 4; ++i)
#pragma unroll
            for (int j = 0; j < 4; ++j) s[i][j] = 0.0f;

#pragma unroll 4
        for (int d4 = 0; d4 < 16; ++d4) {
            const int qc = (d4 ^ ty) << 2;   // rows ty*4+i share row>>2 == ty
            const int kc = (d4 ^ tx) << 2;   // rows tx*4+j share row>>2 == tx
            float4 qv0 = *reinterpret_cast<const float4*>(&Qs[ty * 4 + 0][qc]);
            float4 qv1 = *reinterpret_cast<const float4*>(&Qs[ty * 4 + 1][qc]);
            float4 qv2 = *reinterpret_cast<const float4*>(&Qs[ty * 4 + 2][qc]);
            float4 qv3 = *reinterpret_cast<const float4*>(&Qs[ty * 4 + 3][qc]);
            float4 kv0 = *reinterpret_cast<const float4*>(&Ks[tx * 4 + 0][kc]);
            float4 kv1 = *reinterpret_cast<const float4*>(&Ks[tx * 4 + 1][kc]);
            float4 kv2 = *reinterpret_cast<const float4*>(&Ks[tx * 4 + 2][kc]);
            float4 kv3 = *reinterpret_cast<const float4*>(&Ks[tx * 4 + 3][kc]);
#define DOT4(a, c) (a.x*c.x + a.y*c.y + a.z*c.z + a.w*c.w)
            s[0][0] += DOT4(qv0, kv0); s[0][1] += DOT4(qv0, kv1); s[0][2] += DOT4(qv0, kv2); s[0][3] += DOT4(qv0, kv3);
            s[1][0] += DOT4(qv1, kv0); s[1][1] += DOT4(qv1, kv1); s[1][2] += DOT4(qv1, kv2); s[1][3] += DOT4(qv1, kv3);
            s[2][0] += DOT4(qv2, kv0); s[2][1] += DOT4(qv2, kv1); s[2][2] += DOT4(qv2, kv2); s[2][3] += DOT4(qv2, kv3);
            s[3][0] += DOT4(qv3, kv0); s[3][1] += DOT4(qv3, kv1); s[3][2] += DOT4(qv3, kv2); s[3][3] += DOT4(qv3, kv3);
#undef DOT4
        }

        // causal mask (diagonal tile only)
        if (kt == qt) {
#pragma unroll
            for (int i = 0; i < 4; ++i)
#pragma unroll
                for (int j = 0; j < 4; ++j)
                    if (tx * 4 + j > ty * 4 + i) s[i][j] = -3.4e38f;
        }

        // online softmax, all in registers; rows owned by 16-lane groups
#pragma unroll
        for (int i = 0; i < 4; ++i) {
            float mt = fmaxf(fmaxf(s[i][0], s[i][1]), fmaxf(s[i][2], s[i][3]));
#pragma unroll
            for (int off = 1; off < 16; off <<= 1)
                mt = fmaxf(mt, __shfl_xor(mt, off, 64));
            mt = fmaxf(mt, m_i[i]);
            float alpha = __expf(m_i[i] - mt);
            float p0 = __expf(s[i][0] - mt);
            float p1 = __expf(s[i][1] - mt);
            float p2 = __expf(s[i][2] - mt);
            float p3 = __expf(s[i][3] - mt);
            float sum = p0 + p1 + p2 + p3;
#pragma unroll
            for (int off = 1; off < 16; off <<= 1)
                sum += __shfl_xor(sum, off, 64);
            m_i[i] = mt;
            l_i[i] = l_i[i] * alpha + sum;
#pragma unroll
            for (int j = 0; j < 4; ++j) o_acc[i][j] *= alpha;
            s[i][0] = p0; s[i][1] = p1; s[i][2] = p2; s[i][3] = p3;
        }

        __syncthreads();   // everyone done reading Ks (K) before P overwrite

        // write P into Ks buffer (same swizzle: row>>2 == ty for our rows)
        {
            const int pc = (tx ^ ty) << 2;
#pragma unroll
            for (int i = 0; i < 4; ++i)
                *reinterpret_cast<float4*>(&Ks[ty * 4 + i][pc]) =
                    make_float4(s[i][0], s[i][1], s[i][2], s[i][3]);
        }
        __syncthreads();

        // O += P·V : thread rows ty*4.., out-cols tx*4..
#pragma unroll 4
        for (int k4 = 0; k4 < 16; ++k4) {
            const int pcr = (k4 ^ ty) << 2;
            float4 p0 = *reinterpret_cast<const float4*>(&Ks[ty * 4 + 0][pcr]);
            float4 p1 = *reinterpret_cast<const float4*>(&Ks[ty * 4 + 1][pcr]);
            float4 p2 = *reinterpret_cast<const float4*>(&Ks[ty * 4 + 2][pcr]);
            float4 p3 = *reinterpret_cast<const float4*>(&Ks[ty * 4 + 3][pcr]);
#pragma unroll
            for (int kk = 0; kk < 4; ++kk) {
                float4 vv = *reinterpret_cast<const float4*>(&Vs[k4 * 4 + kk][tx * 4]);
                float pa = (kk == 0) ? p0.x : (kk == 1) ? p0.y : (kk == 2) ? p0.z : p0.w;
                float pb = (kk == 0) ? p1.x : (kk == 1) ? p1.y : (kk == 2) ? p1.z : p1.w;
                float pc_ = (kk == 0) ? p2.x : (kk == 1) ? p2.y : (kk == 2) ? p2.z : p2.w;
                float pd = (kk == 0) ? p3.x : (kk == 1) ? p3.y : (kk == 2) ? p3.z : p3.w;
                o_acc[0][0] += pa * vv.x; o_acc[0][1] += pa * vv.y; o_acc[0][2] += pa * vv.z; o_acc[0][3] += pa * vv.w;
                o_acc[1][0] += pb * vv.x; o_acc[1][1] += pb * vv.y; o_acc[1][2] += pb * vv.z; o_acc[1][3] += pb * vv.w;
                o_acc[2][0] += pc_ * vv.x; o_acc[2][1] += pc_ * vv.y; o_acc[2][2] += pc_ * vv.z; o_acc[2][3] += pc_ * vv.w;
                o_acc[3][0] += pd * vv.x; o_acc[3][1] += pd * vv.y; o_acc[3][2] += pd * vv.z; o_acc[3][3] += pd * vv.w;
            }
        }
    }

    // write O (divide by row sums; all lanes in a group hold l_i)
#pragma unroll
    for (int i = 0; i < 4; ++i) {
        int row = ty * 4 + i;
        float invl = 1.0f / l_i[i];
        float4 ov = make_float4(o_acc[i][0] * invl, o_acc[i][1] * invl,
                                o_acc[i][2] * invl, o_acc[i][3] * invl);
        *reinterpret_cast<float4*>(o + qbase + (size_t)row * QN + tx * 4) = ov;
    }
}

// ---------------- residual add + layernorm (in place on h) ----------------
__global__ __launch_bounds__(256) void add_ln_kernel(
        float* __restrict__ h, const float* __restrict__ delta,
        const float* __restrict__ sc, const float* __restrict__ bi) {
    const int t = blockIdx.x;
    const int d = threadIdx.x;
    __shared__ float red[256];
    const size_t idx = (size_t)t * DD + d;
    float val = h[idx] + delta[idx];
    red[d] = val;
    __syncthreads();
    for (int off = 128; off > 0; off >>= 1) {
        if (d < off) red[d] += red[d + off];
        __syncthreads();
    }
    float mean = red[0] * (1.0f / DD);
    __syncthreads();
    float dv = val - mean;
    red[d] = dv * dv;
    __syncthreads();
    for (int off = 128; off > 0; off >>= 1) {
        if (d < off) red[d] += red[d + off];
        __syncthreads();
    }
    float inv = rsqrtf(red[0] * (1.0f / DD) + 1e-5f);
    h[idx] = dv * inv * sc[d] + bi[d];
}

// ---------------- launch ----------------
extern "C" void kernel_launch(void* const* d_in, const int* in_sizes, int n_in,
                              void* d_out, int out_size, void* d_ws, size_t ws_size,
                              hipStream_t stream) {
    (void)in_sizes; (void)n_in; (void)out_size; (void)ws_size;

    const int*   x    = (const int*)d_in[0];
    const float* emb  = (const float*)d_in[1];
    const float* wq   = (const float*)d_in[2];
    const float* bq   = (const float*)d_in[3];
    const float* wk   = (const float*)d_in[4];
    const float* bk   = (const float*)d_in[5];
    const float* wv   = (const float*)d_in[6];
    const float* bv   = (const float*)d_in[7];
    const float* wo   = (const float*)d_in[8];
    const float* bo   = (const float*)d_in[9];
    const float* ln1s = (const float*)d_in[10];
    const float* ln1b = (const float*)d_in[11];
    const float* w1   = (const float*)d_in[12];
    const float* b1   = (const float*)d_in[13];
    const float* w2   = (const float*)d_in[14];
    const float* b2   = (const float*)d_in[15];
    const float* ln2s = (const float*)d_in[16];
    const float* ln2b = (const float*)d_in[17];
    const float* ow   = (const float*)d_in[18];
    const float* ob   = (const float*)d_in[19];

    float* h    = (float*)d_ws;                 // BS*D
    float* qb   = h + (size_t)BS * DD;          // BS*QN
    float* kb   = qb + (size_t)BS * QN;         // BS*QN
    float* vb   = kb + (size_t)BS * QN;         // BS*QN
    float* t2   = vb + (size_t)BS * QN;         // BS*D
    float* ob_  = qb;                           // attention out aliases q
    float* ffh  = kb;                           // FFN hidden aliases k+v

    embed_pe_kernel<<<BS, 256, 0, stream>>>(x, emb, h);

    for (int i = 0; i < NLAYER; ++i) {
        const float* wqi = wq + (size_t)i * DD * QN;
        const float* wki = wk + (size_t)i * DD * QN;
        const float* wvi = wv + (size_t)i * DD * QN;
        const float* woi = wo + (size_t)i * QN * DD;
        const float* w1i = w1 + (size_t)i * DD * FFD;
        const float* w2i = w2 + (size_t)i * FFD * DD;

        dim3 gq(QN / 64, BS / 64);
        gemm64_kernel<false><<<gq, 256, 0, stream>>>(h, wqi, bq + i * QN, qb, BS, QN, DD);
        gemm64_kernel<false><<<gq, 256, 0, stream>>>(h, wki, bk + i * QN, kb, BS, QN, DD);
        gemm64_kernel<false><<<gq, 256, 0, stream>>>(h, wvi, bv + i * QN, vb, BS, QN, DD);

        flash_attn_kernel<<<dim3(SS / 64, HH, BB), 256, 0, stream>>>(qb, kb, vb, ob_);

        gemm64_kernel<false><<<dim3(DD / 64, BS / 64), 256, 0, stream>>>(
            ob_, woi, bo + i * DD, t2, BS, DD, QN);
        add_ln_kernel<<<BS, 256, 0, stream>>>(h, t2, ln1s + i * DD, ln1b + i * DD);

        gemm64_kernel<true><<<dim3(FFD / 64, BS / 64), 256, 0, stream>>>(
            h, w1i, b1 + i * FFD, ffh, BS, FFD, DD);
        gemm64_kernel<false><<<dim3(DD / 64, BS / 64), 256, 0, stream>>>(
            ffh, w2i, b2 + i * DD, t2, BS, DD, FFD);
        add_ln_kernel<<<BS, 256, 0, stream>>>(h, t2, ln2s + i * DD, ln2b + i * DD);
    }

    gemm64_kernel<false><<<dim3(OUTD / 64, BS / 64), 256, 0, stream>>>(
        h, ow, ob, (float*)d_out, BS, OUTD, DD);
}

// Round 3
// 2472.944 us; speedup vs baseline: 3.0307x; 1.9399x over previous
//
#include <hip/hip_runtime.h>

// ---------------- problem constants ----------------
#define BB   32
#define SS   512
#define DD   256
#define HH   8
#define HDIM 64
#define NLAYER 5
#define FFD  1024
#define OUTD 4096
#define QN   512            // H*HD
#define BS   (BB*SS)        // 16384 tokens

typedef short bf16x8 __attribute__((ext_vector_type(8)));
typedef float f32x4  __attribute__((ext_vector_type(4)));

__device__ __forceinline__ ushort f2bf(float f) {
    union { float f; unsigned u; } c; c.f = f;
    unsigned u = c.u;
    return (ushort)((u + 0x7fffu + ((u >> 16) & 1u)) >> 16);  // RNE
}
__device__ __forceinline__ float bf2f(unsigned b) {
    union { unsigned u; float f; } c; c.u = b << 16;
    return c.f;
}

// ---------------- embedding + positional encoding ----------------
__global__ __launch_bounds__(256) void embed_pe_kernel(
        const int* __restrict__ x, const float* __restrict__ emb,
        float* __restrict__ h, ushort* __restrict__ hb) {
    int t = blockIdx.x;
    int d = threadIdx.x;
    int pos = t % SS;
    int tok = x[t];
    float e = emb[(size_t)tok * DD + d];
    float expo = -(float)(d & ~1) / (float)DD;
    float ang = (float)pos * powf(10000.0f, expo);
    float pe = (d & 1) ? cosf(ang) : sinf(ang);
    float val = e + pe;
    h[(size_t)t * DD + d] = val;
    hb[(size_t)t * DD + d] = f2bf(val);
}

// ---------------- weight convert + transpose: W[K][N] f32 -> Wt[N][K] bf16 ----
__global__ __launch_bounds__(256) void convw_kernel(
        const float* __restrict__ W, ushort* __restrict__ Wt, int K, int N) {
    __shared__ float t[32][33];
    const int tid = threadIdx.x;
    const int tx = tid & 31, ty = tid >> 5;   // 32 x 8
    const int n0 = blockIdx.x * 32, k0 = blockIdx.y * 32;
#pragma unroll
    for (int i = 0; i < 4; ++i)
        t[ty + i * 8][tx] = W[(size_t)(k0 + ty + i * 8) * N + n0 + tx];
    __syncthreads();
#pragma unroll
    for (int i = 0; i < 4; ++i)
        Wt[(size_t)(n0 + ty + i * 8) * K + k0 + tx] = f2bf(t[tx][ty + i * 8]);
}

// ---------------- MFMA bf16 GEMM ----------------
// C[M][N] = A[M][K](bf16) * Wt[N][K]^T(bf16) + bias.  128x128 tile, 4 waves
// (2x2 of 64x64), BK=32, mfma_f32_16x16x32_bf16.
// LDS tiles [128 rows][4 granules of 8 bf16]; granule swizzled g^((row>>1)&3)
// so fragment b128 reads are 2-way (free) and staging writes are conflict-free.
// D layout (m89-verified): row=(lane>>4)*4+reg, col=lane&15.
template<bool RELU, bool OBF>
__global__ __launch_bounds__(256) void gemm_mfma_kernel(
        const ushort* __restrict__ A, const ushort* __restrict__ Bt,
        const float* __restrict__ bias, void* __restrict__ Cout,
        int M, int N, int K) {
    __shared__ ushort sA[128 * 32];
    __shared__ ushort sB[128 * 32];

    const int tid  = threadIdx.x;
    const int lane = tid & 63;
    const int wave = tid >> 6;      // 0..3
    const int wr   = wave >> 1;     // wave row 0..1
    const int wc   = wave & 1;      // wave col 0..1
    const int fr   = lane & 15;
    const int fq   = lane >> 4;     // 0..3
    const int m0 = blockIdx.y * 128;
    const int n0 = blockIdx.x * 128;

    f32x4 acc[4][4];
#pragma unroll
    for (int mi = 0; mi < 4; ++mi)
#pragma unroll
        for (int ni = 0; ni < 4; ++ni)
            acc[mi][ni] = (f32x4){0.0f, 0.0f, 0.0f, 0.0f};

    for (int k0 = 0; k0 < K; k0 += 32) {
        // stage: 512 granules (16B) each for A and Bt; thread does 2 of each
#pragma unroll
        for (int it = 0; it < 2; ++it) {
            const int gi  = tid + it * 256;       // 0..511
            const int row = gi >> 2, g = gi & 3;
            const int gs  = g ^ ((row >> 1) & 3);
            const uint4 av = *reinterpret_cast<const uint4*>(
                A + (size_t)(m0 + row) * K + k0 + g * 8);
            *reinterpret_cast<uint4*>(&sA[row * 32 + gs * 8]) = av;
            const uint4 bv = *reinterpret_cast<const uint4*>(
                Bt + (size_t)(n0 + row) * K + k0 + g * 8);
            *reinterpret_cast<uint4*>(&sB[row * 32 + gs * 8]) = bv;
        }
        __syncthreads();

        bf16x8 af[4], bfr[4];
#pragma unroll
        for (int mi = 0; mi < 4; ++mi) {
            const int row = wr * 64 + mi * 16 + fr;
            const int gs  = fq ^ ((row >> 1) & 3);
            af[mi] = *reinterpret_cast<const bf16x8*>(&sA[row * 32 + gs * 8]);
        }
#pragma unroll
        for (int ni = 0; ni < 4; ++ni) {
            const int row = wc * 64 + ni * 16 + fr;
            const int gs  = fq ^ ((row >> 1) & 3);
            bfr[ni] = *reinterpret_cast<const bf16x8*>(&sB[row * 32 + gs * 8]);
        }
#pragma unroll
        for (int mi = 0; mi < 4; ++mi)
#pragma unroll
            for (int ni = 0; ni < 4; ++ni)
                acc[mi][ni] = __builtin_amdgcn_mfma_f32_16x16x32_bf16(
                    af[mi], bfr[ni], acc[mi][ni], 0, 0, 0);
        __syncthreads();
    }

    // epilogue
#pragma unroll
    for (int ni = 0; ni < 4; ++ni) {
        const int col = n0 + wc * 64 + ni * 16 + fr;
        const float bv = bias[col];
#pragma unroll
        for (int mi = 0; mi < 4; ++mi) {
#pragma unroll
            for (int r = 0; r < 4; ++r) {
                const int row = m0 + wr * 64 + mi * 16 + fq * 4 + r;
                float v = acc[mi][ni][r] + bv;
                if (RELU) v = fmaxf(v, 0.0f);
                if (OBF)
                    ((ushort*)Cout)[(size_t)row * N + col] = f2bf(v);
                else
                    ((float*)Cout)[(size_t)row * N + col] = v;
            }
        }
    }
}

// ---------------- flash attention (bf16 I/O, f32 compute) ----------------
// One block per (q-tile of 64, head, batch). q,k,v,o: bf16 [BS, QN], col=h*64+d.
// o aliases q safely (block reads only its own staged Q region, writes same).
__global__ __launch_bounds__(256) void flash_attn_kernel(
        const ushort* __restrict__ q, const ushort* __restrict__ k,
        const ushort* __restrict__ v, ushort* __restrict__ o) {
    const int qt  = blockIdx.x;   // 0..7
    const int hh  = blockIdx.y;   // 0..7
    const int b   = blockIdx.z;   // 0..31
    const int tid = threadIdx.x;
    const int tx  = tid & 15;
    const int ty  = tid >> 4;

    __shared__ float Qs[64][64];
    __shared__ float Ks[64][64];  // K during QK^T, P during PV
    __shared__ float Vs[64][64];

    const size_t qbase = ((size_t)(b * SS + qt * 64)) * QN + hh * HDIM;

    // load Q tile (64x64 bf16 -> f32), pre-scaled by 0.125, swizzled
#pragma unroll
    for (int it = 0; it < 2; ++it) {
        int idx = tid + it * 256;            // 0..511
        int row = idx >> 3, c8 = idx & 7;    // 8 bf16 per thread
        uint4 raw = *reinterpret_cast<const uint4*>(
            q + qbase + (size_t)row * QN + c8 * 8);
        int g0 = ((2 * c8) ^ (row >> 2)) << 2;
        int g1 = ((2 * c8 + 1) ^ (row >> 2)) << 2;
        *reinterpret_cast<float4*>(&Qs[row][g0]) = make_float4(
            bf2f(raw.x & 0xffff) * 0.125f, bf2f(raw.x >> 16) * 0.125f,
            bf2f(raw.y & 0xffff) * 0.125f, bf2f(raw.y >> 16) * 0.125f);
        *reinterpret_cast<float4*>(&Qs[row][g1]) = make_float4(
            bf2f(raw.z & 0xffff) * 0.125f, bf2f(raw.z >> 16) * 0.125f,
            bf2f(raw.w & 0xffff) * 0.125f, bf2f(raw.w >> 16) * 0.125f);
    }

    float o_acc[4][4];
    float m_i[4], l_i[4];
#pragma unroll
    for (int i = 0; i < 4; ++i) {
        m_i[i] = -3.4e38f;
        l_i[i] = 0.0f;
#pragma unroll
        for (int j = 0; j < 4; ++j) o_acc[i][j] = 0.0f;
    }

    for (int kt = 0; kt <= qt; ++kt) {
        __syncthreads();
        const size_t kbase = ((size_t)(b * SS + kt * 64)) * QN + hh * HDIM;
#pragma unroll
        for (int it = 0; it < 2; ++it) {
            int idx = tid + it * 256;
            int row = idx >> 3, c8 = idx & 7;
            uint4 kraw = *reinterpret_cast<const uint4*>(
                k + kbase + (size_t)row * QN + c8 * 8);
            int g0 = ((2 * c8) ^ (row >> 2)) << 2;
            int g1 = ((2 * c8 + 1) ^ (row >> 2)) << 2;
            *reinterpret_cast<float4*>(&Ks[row][g0]) = make_float4(
                bf2f(kraw.x & 0xffff), bf2f(kraw.x >> 16),
                bf2f(kraw.y & 0xffff), bf2f(kraw.y >> 16));
            *reinterpret_cast<float4*>(&Ks[row][g1]) = make_float4(
                bf2f(kraw.z & 0xffff), bf2f(kraw.z >> 16),
                bf2f(kraw.w & 0xffff), bf2f(kraw.w >> 16));
            uint4 vraw = *reinterpret_cast<const uint4*>(
                v + kbase + (size_t)row * QN + c8 * 8);
            *reinterpret_cast<float4*>(&Vs[row][c8 * 8]) = make_float4(
                bf2f(vraw.x & 0xffff), bf2f(vraw.x >> 16),
                bf2f(vraw.y & 0xffff), bf2f(vraw.y >> 16));
            *reinterpret_cast<float4*>(&Vs[row][c8 * 8 + 4]) = make_float4(
                bf2f(vraw.z & 0xffff), bf2f(vraw.z >> 16),
                bf2f(vraw.w & 0xffff), bf2f(vraw.w >> 16));
        }
        __syncthreads();

        float s[4][4];
#pragma unroll
        for (int i = 0; i < 4; ++i)
#pragma unroll
            for (int j = 0; j < 4; ++j) s[i][j] = 0.0f;

#pragma unroll 4
        for (int d4 = 0; d4 < 16; ++d4) {
            const int qc = (d4 ^ ty) << 2;
            const int kc = (d4 ^ tx) << 2;
            float4 qv0 = *reinterpret_cast<const float4*>(&Qs[ty * 4 + 0][qc]);
            float4 qv1 = *reinterpret_cast<const float4*>(&Qs[ty * 4 + 1][qc]);
            float4 qv2 = *reinterpret_cast<const float4*>(&Qs[ty * 4 + 2][qc]);
            float4 qv3 = *reinterpret_cast<const float4*>(&Qs[ty * 4 + 3][qc]);
            float4 kv0 = *reinterpret_cast<const float4*>(&Ks[tx * 4 + 0][kc]);
            float4 kv1 = *reinterpret_cast<const float4*>(&Ks[tx * 4 + 1][kc]);
            float4 kv2 = *reinterpret_cast<const float4*>(&Ks[tx * 4 + 2][kc]);
            float4 kv3 = *reinterpret_cast<const float4*>(&Ks[tx * 4 + 3][kc]);
#define DOT4(a, c) (a.x*c.x + a.y*c.y + a.z*c.z + a.w*c.w)
            s[0][0] += DOT4(qv0, kv0); s[0][1] += DOT4(qv0, kv1); s[0][2] += DOT4(qv0, kv2); s[0][3] += DOT4(qv0, kv3);
            s[1][0] += DOT4(qv1, kv0); s[1][1] += DOT4(qv1, kv1); s[1][2] += DOT4(qv1, kv2); s[1][3] += DOT4(qv1, kv3);
            s[2][0] += DOT4(qv2, kv0); s[2][1] += DOT4(qv2, kv1); s[2][2] += DOT4(qv2, kv2); s[2][3] += DOT4(qv2, kv3);
            s[3][0] += DOT4(qv3, kv0); s[3][1] += DOT4(qv3, kv1); s[3][2] += DOT4(qv3, kv2); s[3][3] += DOT4(qv3, kv3);
#undef DOT4
        }

        if (kt == qt) {
#pragma unroll
            for (int i = 0; i < 4; ++i)
#pragma unroll
                for (int j = 0; j < 4; ++j)
                    if (tx * 4 + j > ty * 4 + i) s[i][j] = -3.4e38f;
        }

        // online softmax in registers
#pragma unroll
        for (int i = 0; i < 4; ++i) {
            float mt = fmaxf(fmaxf(s[i][0], s[i][1]), fmaxf(s[i][2], s[i][3]));
#pragma unroll
            for (int off = 1; off < 16; off <<= 1)
                mt = fmaxf(mt, __shfl_xor(mt, off, 64));
            mt = fmaxf(mt, m_i[i]);
            float alpha = __expf(m_i[i] - mt);
            float p0 = __expf(s[i][0] - mt);
            float p1 = __expf(s[i][1] - mt);
            float p2 = __expf(s[i][2] - mt);
            float p3 = __expf(s[i][3] - mt);
            float sum = p0 + p1 + p2 + p3;
#pragma unroll
            for (int off = 1; off < 16; off <<= 1)
                sum += __shfl_xor(sum, off, 64);
            m_i[i] = mt;
            l_i[i] = l_i[i] * alpha + sum;
#pragma unroll
            for (int j = 0; j < 4; ++j) o_acc[i][j] *= alpha;
            s[i][0] = p0; s[i][1] = p1; s[i][2] = p2; s[i][3] = p3;
        }

        __syncthreads();   // all K-reads done before P overwrite

        {
            const int pc = (tx ^ ty) << 2;
#pragma unroll
            for (int i = 0; i < 4; ++i)
                *reinterpret_cast<float4*>(&Ks[ty * 4 + i][pc]) =
                    make_float4(s[i][0], s[i][1], s[i][2], s[i][3]);
        }
        __syncthreads();

#pragma unroll 4
        for (int k4 = 0; k4 < 16; ++k4) {
            const int pcr = (k4 ^ ty) << 2;
            float4 p0 = *reinterpret_cast<const float4*>(&Ks[ty * 4 + 0][pcr]);
            float4 p1 = *reinterpret_cast<const float4*>(&Ks[ty * 4 + 1][pcr]);
            float4 p2 = *reinterpret_cast<const float4*>(&Ks[ty * 4 + 2][pcr]);
            float4 p3 = *reinterpret_cast<const float4*>(&Ks[ty * 4 + 3][pcr]);
#pragma unroll
            for (int kk = 0; kk < 4; ++kk) {
                float4 vv = *reinterpret_cast<const float4*>(&Vs[k4 * 4 + kk][tx * 4]);
                float pa = (kk == 0) ? p0.x : (kk == 1) ? p0.y : (kk == 2) ? p0.z : p0.w;
                float pb = (kk == 0) ? p1.x : (kk == 1) ? p1.y : (kk == 2) ? p1.z : p1.w;
                float pc_ = (kk == 0) ? p2.x : (kk == 1) ? p2.y : (kk == 2) ? p2.z : p2.w;
                float pd = (kk == 0) ? p3.x : (kk == 1) ? p3.y : (kk == 2) ? p3.z : p3.w;
                o_acc[0][0] += pa * vv.x; o_acc[0][1] += pa * vv.y; o_acc[0][2] += pa * vv.z; o_acc[0][3] += pa * vv.w;
                o_acc[1][0] += pb * vv.x; o_acc[1][1] += pb * vv.y; o_acc[1][2] += pb * vv.z; o_acc[1][3] += pb * vv.w;
                o_acc[2][0] += pc_ * vv.x; o_acc[2][1] += pc_ * vv.y; o_acc[2][2] += pc_ * vv.z; o_acc[2][3] += pc_ * vv.w;
                o_acc[3][0] += pd * vv.x; o_acc[3][1] += pd * vv.y; o_acc[3][2] += pd * vv.z; o_acc[3][3] += pd * vv.w;
            }
        }
    }

    // write O as bf16
#pragma unroll
    for (int i = 0; i < 4; ++i) {
        int row = ty * 4 + i;
        float invl = 1.0f / l_i[i];
        ushort4 ov = make_ushort4(f2bf(o_acc[i][0] * invl), f2bf(o_acc[i][1] * invl),
                                  f2bf(o_acc[i][2] * invl), f2bf(o_acc[i][3] * invl));
        *reinterpret_cast<ushort4*>(o + qbase + (size_t)row * QN + tx * 4) = ov;
    }
}

// ---------------- residual add + layernorm (in place on h; emits bf16 copy) ---
__global__ __launch_bounds__(256) void add_ln_kernel(
        float* __restrict__ h, const float* __restrict__ delta,
        const float* __restrict__ sc, const float* __restrict__ bi,
        ushort* __restrict__ hb) {
    const int t = blockIdx.x;
    const int d = threadIdx.x;
    __shared__ float p1[4], p2[4];
    const size_t idx = (size_t)t * DD + d;
    float val = h[idx] + delta[idx];
    float s = val;
#pragma unroll
    for (int off = 1; off < 64; off <<= 1) s += __shfl_xor(s, off, 64);
    if ((d & 63) == 0) p1[d >> 6] = s;
    __syncthreads();
    float mean = (p1[0] + p1[1] + p1[2] + p1[3]) * (1.0f / DD);
    float dv = val - mean;
    float vs = dv * dv;
#pragma unroll
    for (int off = 1; off < 64; off <<= 1) vs += __shfl_xor(vs, off, 64);
    if ((d & 63) == 0) p2[d >> 6] = vs;
    __syncthreads();
    float inv = rsqrtf((p2[0] + p2[1] + p2[2] + p2[3]) * (1.0f / DD) + 1e-5f);
    float r = dv * inv * sc[d] + bi[d];
    h[idx] = r;
    hb[idx] = f2bf(r);
}

// ---------------- launch ----------------
extern "C" void kernel_launch(void* const* d_in, const int* in_sizes, int n_in,
                              void* d_out, int out_size, void* d_ws, size_t ws_size,
                              hipStream_t stream) {
    (void)in_sizes; (void)n_in; (void)out_size; (void)ws_size;

    const int*   x    = (const int*)d_in[0];
    const float* emb  = (const float*)d_in[1];
    const float* wq   = (const float*)d_in[2];
    const float* bq   = (const float*)d_in[3];
    const float* wk   = (const float*)d_in[4];
    const float* bk   = (const float*)d_in[5];
    const float* wv   = (const float*)d_in[6];
    const float* bv   = (const float*)d_in[7];
    const float* wo   = (const float*)d_in[8];
    const float* bo   = (const float*)d_in[9];
    const float* ln1s = (const float*)d_in[10];
    const float* ln1b = (const float*)d_in[11];
    const float* w1   = (const float*)d_in[12];
    const float* b1   = (const float*)d_in[13];
    const float* w2   = (const float*)d_in[14];
    const float* b2   = (const float*)d_in[15];
    const float* ln2s = (const float*)d_in[16];
    const float* ln2b = (const float*)d_in[17];
    const float* ow   = (const float*)d_in[18];
    const float* ob   = (const float*)d_in[19];

    // workspace layout (~101 MB)
    char* ws = (char*)d_ws;
    float*  h   = (float*)ws;   ws += (size_t)BS * DD * 4;    // 16 MB
    ushort* hbf = (ushort*)ws;  ws += (size_t)BS * DD * 2;    //  8 MB
    ushort* qb  = (ushort*)ws;  ws += (size_t)BS * QN * 2;    // 16 MB
    ushort* kb  = (ushort*)ws;  ws += (size_t)BS * QN * 2;    // 16 MB
    ushort* vb  = (ushort*)ws;  ws += (size_t)BS * QN * 2;    // 16 MB
    float*  t2  = (float*)ws;   ws += (size_t)BS * DD * 4;    // 16 MB
    ushort* wqt = (ushort*)ws;  ws += (size_t)NLAYER * QN * DD * 2;
    ushort* wkt = (ushort*)ws;  ws += (size_t)NLAYER * QN * DD * 2;
    ushort* wvt = (ushort*)ws;  ws += (size_t)NLAYER * QN * DD * 2;
    ushort* wot = (ushort*)ws;  ws += (size_t)NLAYER * DD * QN * 2;
    ushort* w1t = (ushort*)ws;  ws += (size_t)NLAYER * FFD * DD * 2;
    ushort* w2t = (ushort*)ws;  ws += (size_t)NLAYER * DD * FFD * 2;
    ushort* owt = (ushort*)ws;  ws += (size_t)OUTD * DD * 2;
    ushort* ao  = qb;           // attention out aliases q (bf16, same layout)
    ushort* ffh = kb;           // FFN hidden (32 MB) aliases k+v

    // weight conversion (f32 [K][N] -> bf16 [N][K])
    for (int i = 0; i < NLAYER; ++i) {
        convw_kernel<<<dim3(QN / 32, DD / 32), 256, 0, stream>>>(
            wq + (size_t)i * DD * QN, wqt + (size_t)i * QN * DD, DD, QN);
        convw_kernel<<<dim3(QN / 32, DD / 32), 256, 0, stream>>>(
            wk + (size_t)i * DD * QN, wkt + (size_t)i * QN * DD, DD, QN);
        convw_kernel<<<dim3(QN / 32, DD / 32), 256, 0, stream>>>(
            wv + (size_t)i * DD * QN, wvt + (size_t)i * QN * DD, DD, QN);
        convw_kernel<<<dim3(DD / 32, QN / 32), 256, 0, stream>>>(
            wo + (size_t)i * QN * DD, wot + (size_t)i * DD * QN, QN, DD);
        convw_kernel<<<dim3(FFD / 32, DD / 32), 256, 0, stream>>>(
            w1 + (size_t)i * DD * FFD, w1t + (size_t)i * FFD * DD, DD, FFD);
        convw_kernel<<<dim3(DD / 32, FFD / 32), 256, 0, stream>>>(
            w2 + (size_t)i * FFD * DD, w2t + (size_t)i * DD * FFD, FFD, DD);
    }
    convw_kernel<<<dim3(OUTD / 32, DD / 32), 256, 0, stream>>>(ow, owt, DD, OUTD);

    embed_pe_kernel<<<BS, 256, 0, stream>>>(x, emb, h, hbf);

    for (int i = 0; i < NLAYER; ++i) {
        dim3 gq(QN / 128, BS / 128);
        gemm_mfma_kernel<false, true><<<gq, 256, 0, stream>>>(
            hbf, wqt + (size_t)i * QN * DD, bq + i * QN, qb, BS, QN, DD);
        gemm_mfma_kernel<false, true><<<gq, 256, 0, stream>>>(
            hbf, wkt + (size_t)i * QN * DD, bk + i * QN, kb, BS, QN, DD);
        gemm_mfma_kernel<false, true><<<gq, 256, 0, stream>>>(
            hbf, wvt + (size_t)i * QN * DD, bv + i * QN, vb, BS, QN, DD);

        flash_attn_kernel<<<dim3(SS / 64, HH, BB), 256, 0, stream>>>(qb, kb, vb, ao);

        gemm_mfma_kernel<false, false><<<dim3(DD / 128, BS / 128), 256, 0, stream>>>(
            ao, wot + (size_t)i * DD * QN, bo + i * DD, t2, BS, DD, QN);
        add_ln_kernel<<<BS, 256, 0, stream>>>(h, t2, ln1s + i * DD, ln1b + i * DD, hbf);

        gemm_mfma_kernel<true, true><<<dim3(FFD / 128, BS / 128), 256, 0, stream>>>(
            hbf, w1t + (size_t)i * FFD * DD, b1 + i * FFD, ffh, BS, FFD, DD);
        gemm_mfma_kernel<false, false><<<dim3(DD / 128, BS / 128), 256, 0, stream>>>(
            ffh, w2t + (size_t)i * DD * FFD, b2 + i * DD, t2, BS, DD, FFD);
        add_ln_kernel<<<BS, 256, 0, stream>>>(h, t2, ln2s + i * DD, ln2b + i * DD, hbf);
    }

    gemm_mfma_kernel<false, false><<<dim3(OUTD / 128, BS / 128), 256, 0, stream>>>(
        hbf, owt, ob, (float*)d_out, BS, OUTD, DD);
}

// Round 4
// 1443.137 us; speedup vs baseline: 5.1934x; 1.7136x over previous
//
#include <hip/hip_runtime.h>

// ---------------- problem constants ----------------
#define BB   32
#define SS   512
#define DD   256
#define HH   8
#define HDIM 64
#define NLAYER 5
#define FFD  1024
#define OUTD 4096
#define QN   512            // H*HD
#define BS   (BB*SS)        // 16384 tokens

typedef short bf16x8 __attribute__((ext_vector_type(8)));
typedef float f32x4  __attribute__((ext_vector_type(4)));

__device__ __forceinline__ ushort f2bf(float f) {
    union { float f; unsigned u; } c; c.f = f;
    unsigned u = c.u;
    return (ushort)((u + 0x7fffu + ((u >> 16) & 1u)) >> 16);  // RNE
}
__device__ __forceinline__ float bf2f(unsigned b) {
    union { unsigned u; float f; } c; c.u = b << 16;
    return c.f;
}

// ---------------- embedding + positional encoding ----------------
__global__ __launch_bounds__(256) void embed_pe_kernel(
        const int* __restrict__ x, const float* __restrict__ emb,
        float* __restrict__ h, ushort* __restrict__ hb) {
    int t = blockIdx.x;
    int d = threadIdx.x;
    int pos = t % SS;
    int tok = x[t];
    float e = emb[(size_t)tok * DD + d];
    float expo = -(float)(d & ~1) / (float)DD;
    float ang = (float)pos * powf(10000.0f, expo);
    float pe = (d & 1) ? cosf(ang) : sinf(ang);
    float val = e + pe;
    h[(size_t)t * DD + d] = val;
    hb[(size_t)t * DD + d] = f2bf(val);
}

// ---------------- weight convert + transpose: W[K][N] f32 -> Wt[N][K] bf16 ----
__global__ __launch_bounds__(256) void convw_kernel(
        const float* __restrict__ W, ushort* __restrict__ Wt, int K, int N) {
    __shared__ float t[32][33];
    const int tid = threadIdx.x;
    const int tx = tid & 31, ty = tid >> 5;   // 32 x 8
    const int n0 = blockIdx.x * 32, k0 = blockIdx.y * 32;
#pragma unroll
    for (int i = 0; i < 4; ++i)
        t[ty + i * 8][tx] = W[(size_t)(k0 + ty + i * 8) * N + n0 + tx];
    __syncthreads();
#pragma unroll
    for (int i = 0; i < 4; ++i)
        Wt[(size_t)(n0 + ty + i * 8) * K + k0 + tx] = f2bf(t[tx][ty + i * 8]);
}

// ---------------- MFMA bf16 GEMM ----------------
// C[M][N] = A[M][K](bf16) * Wt[N][K]^T(bf16) + bias.  128x128 tile, 4 waves
// (2x2 of 64x64), BK=32, mfma_f32_16x16x32_bf16.
template<bool RELU, bool OBF>
__global__ __launch_bounds__(256) void gemm_mfma_kernel(
        const ushort* __restrict__ A, const ushort* __restrict__ Bt,
        const float* __restrict__ bias, void* __restrict__ Cout,
        int M, int N, int K) {
    __shared__ ushort sA[128 * 32];
    __shared__ ushort sB[128 * 32];

    const int tid  = threadIdx.x;
    const int lane = tid & 63;
    const int wave = tid >> 6;      // 0..3
    const int wr   = wave >> 1;     // wave row 0..1
    const int wc   = wave & 1;      // wave col 0..1
    const int fr   = lane & 15;
    const int fq   = lane >> 4;     // 0..3
    const int m0 = blockIdx.y * 128;
    const int n0 = blockIdx.x * 128;

    f32x4 acc[4][4];
#pragma unroll
    for (int mi = 0; mi < 4; ++mi)
#pragma unroll
        for (int ni = 0; ni < 4; ++ni)
            acc[mi][ni] = (f32x4){0.0f, 0.0f, 0.0f, 0.0f};

    for (int k0 = 0; k0 < K; k0 += 32) {
#pragma unroll
        for (int it = 0; it < 2; ++it) {
            const int gi  = tid + it * 256;       // 0..511
            const int row = gi >> 2, g = gi & 3;
            const int gs  = g ^ ((row >> 1) & 3);
            const uint4 av = *reinterpret_cast<const uint4*>(
                A + (size_t)(m0 + row) * K + k0 + g * 8);
            *reinterpret_cast<uint4*>(&sA[row * 32 + gs * 8]) = av;
            const uint4 bv = *reinterpret_cast<const uint4*>(
                Bt + (size_t)(n0 + row) * K + k0 + g * 8);
            *reinterpret_cast<uint4*>(&sB[row * 32 + gs * 8]) = bv;
        }
        __syncthreads();

        bf16x8 af[4], bfr[4];
#pragma unroll
        for (int mi = 0; mi < 4; ++mi) {
            const int row = wr * 64 + mi * 16 + fr;
            const int gs  = fq ^ ((row >> 1) & 3);
            af[mi] = *reinterpret_cast<const bf16x8*>(&sA[row * 32 + gs * 8]);
        }
#pragma unroll
        for (int ni = 0; ni < 4; ++ni) {
            const int row = wc * 64 + ni * 16 + fr;
            const int gs  = fq ^ ((row >> 1) & 3);
            bfr[ni] = *reinterpret_cast<const bf16x8*>(&sB[row * 32 + gs * 8]);
        }
#pragma unroll
        for (int mi = 0; mi < 4; ++mi)
#pragma unroll
            for (int ni = 0; ni < 4; ++ni)
                acc[mi][ni] = __builtin_amdgcn_mfma_f32_16x16x32_bf16(
                    af[mi], bfr[ni], acc[mi][ni], 0, 0, 0);
        __syncthreads();
    }

#pragma unroll
    for (int ni = 0; ni < 4; ++ni) {
        const int col = n0 + wc * 64 + ni * 16 + fr;
        const float bv = bias[col];
#pragma unroll
        for (int mi = 0; mi < 4; ++mi) {
#pragma unroll
            for (int r = 0; r < 4; ++r) {
                const int row = m0 + wr * 64 + mi * 16 + fq * 4 + r;
                float v = acc[mi][ni][r] + bv;
                if (RELU) v = fmaxf(v, 0.0f);
                if (OBF)
                    ((ushort*)Cout)[(size_t)row * N + col] = f2bf(v);
                else
                    ((float*)Cout)[(size_t)row * N + col] = v;
            }
        }
    }
}

// ---------------- flash attention (MFMA, bf16) ----------------
// One block per (q-tile 64, head, batch); 4 waves, wave w owns q-rows w*16..+15.
// Tiles in LDS (bf16): Qs,Ks row-major [row][64] with granule swizzle g^(row&7);
// Vt transposed [d][kv] with kv-granule swizzle g^(d&7); Ps [q][kv] per-wave-
// private slices (no barrier needed; same-wave LDS ops are in-order).
// mfma_f32_16x16x32_bf16 layout (verified by the passing GEMM): A: row=lane&15,
// k=(lane>>4)*8+i; D: col=lane&15, row=(lane>>4)*4+reg.
__global__ __launch_bounds__(256) void flash_attn_kernel(
        const ushort* __restrict__ q, const ushort* __restrict__ k,
        const ushort* __restrict__ v, ushort* __restrict__ o) {
    const int qt  = blockIdx.x;   // 0..7
    const int hh  = blockIdx.y;   // 0..7
    const int b   = blockIdx.z;   // 0..31
    const int tid = threadIdx.x;
    const int l   = tid & 63;
    const int w   = tid >> 6;     // wave id = q-slice
    const int lf  = l & 15;
    const int lg  = l >> 4;

    __shared__ ushort Qs[64 * 64];
    __shared__ ushort Ks[64 * 64];
    __shared__ ushort Vt[64 * 64];   // [d][kv]
    __shared__ ushort Ps[64 * 64];   // [q][kv]

    const size_t qbase = ((size_t)(b * SS + qt * 64)) * QN + hh * HDIM;

    // stage Q (row-major, swizzled): 512 granules, 2 per thread
#pragma unroll
    for (int it = 0; it < 2; ++it) {
        int gi = tid + it * 256;
        int row = gi >> 3, g = gi & 7;
        uint4 val = *reinterpret_cast<const uint4*>(
            q + qbase + (size_t)row * QN + g * 8);
        *reinterpret_cast<uint4*>(&Qs[row * 64 + ((g ^ (row & 7)) << 3)]) = val;
    }

    f32x4 o_acc[4];
    float m_i[4], l_i[4];
#pragma unroll
    for (int r = 0; r < 4; ++r) { m_i[r] = -3.0e38f; l_i[r] = 0.0f; }
#pragma unroll
    for (int ni = 0; ni < 4; ++ni) o_acc[ni] = (f32x4){0.f, 0.f, 0.f, 0.f};

    const int vkv  = l;          // V-staging: lane owns kv-row l
    const int vgd  = w * 2;      // V-staging: wave w covers d-granules 2w,2w+1

    for (int kt = 0; kt <= qt; ++kt) {
        const size_t kbase = ((size_t)(b * SS + kt * 64)) * QN + hh * HDIM;
        // stage K row-major swizzled
#pragma unroll
        for (int it = 0; it < 2; ++it) {
            int gi = tid + it * 256;
            int row = gi >> 3, g = gi & 7;
            uint4 val = *reinterpret_cast<const uint4*>(
                k + kbase + (size_t)row * QN + g * 8);
            *reinterpret_cast<uint4*>(&Ks[row * 64 + ((g ^ (row & 7)) << 3)]) = val;
        }
        // stage V transposed: lane reads V[kv=l][d-granule], scatters b16 down
        // column kv; per-instr all lanes share d -> banks spread by kv (2-way).
#pragma unroll
        for (int sel = 0; sel < 2; ++sel) {
            const int gd = vgd + sel;
            uint4 raw = *reinterpret_cast<const uint4*>(
                v + kbase + (size_t)vkv * QN + gd * 8);
            unsigned e[4] = {raw.x, raw.y, raw.z, raw.w};
#pragma unroll
            for (int j = 0; j < 8; ++j) {
                int d = gd * 8 + j;
                ushort val = (ushort)((e[j >> 1] >> ((j & 1) * 16)) & 0xffff);
                Vt[d * 64 + (((vkv >> 3) ^ (d & 7)) << 3) + (vkv & 7)] = val;
            }
        }
        __syncthreads();

        // ---- S = Q . K^T (per wave: 16q x 64kv) ----
        f32x4 st[4];
#pragma unroll
        for (int ni = 0; ni < 4; ++ni) st[ni] = (f32x4){0.f, 0.f, 0.f, 0.f};
        const int arow = w * 16 + lf;
#pragma unroll
        for (int ks = 0; ks < 2; ++ks) {
            bf16x8 aq = *reinterpret_cast<const bf16x8*>(
                &Qs[arow * 64 + (((ks * 4 + lg) ^ (arow & 7)) << 3)]);
#pragma unroll
            for (int ni = 0; ni < 4; ++ni) {
                const int brow = ni * 16 + lf;
                bf16x8 bk = *reinterpret_cast<const bf16x8*>(
                    &Ks[brow * 64 + (((ks * 4 + lg) ^ (brow & 7)) << 3)]);
                st[ni] = __builtin_amdgcn_mfma_f32_16x16x32_bf16(aq, bk, st[ni], 0, 0, 0);
            }
        }
        // scale 1/sqrt(64)
#pragma unroll
        for (int ni = 0; ni < 4; ++ni) st[ni] *= 0.125f;

        // causal mask on diagonal tile
        if (kt == qt) {
#pragma unroll
            for (int ni = 0; ni < 4; ++ni)
#pragma unroll
                for (int r = 0; r < 4; ++r)
                    if (16 * ni + lf > w * 16 + 4 * lg + r) st[ni][r] = -1.0e30f;
        }

        // ---- online softmax (lane owns q-rows w*16+4*lg+r, kv cols lf+16ni) ----
#pragma unroll
        for (int r = 0; r < 4; ++r) {
            float mx = fmaxf(fmaxf(st[0][r], st[1][r]), fmaxf(st[2][r], st[3][r]));
#pragma unroll
            for (int off = 1; off < 16; off <<= 1)
                mx = fmaxf(mx, __shfl_xor(mx, off, 64));
            float mnew = fmaxf(m_i[r], mx);
            float alpha = __expf(m_i[r] - mnew);
            float sum = 0.0f;
#pragma unroll
            for (int ni = 0; ni < 4; ++ni) {
                float p = __expf(st[ni][r] - mnew);
                st[ni][r] = p;
                sum += p;
            }
#pragma unroll
            for (int off = 1; off < 16; off <<= 1)
                sum += __shfl_xor(sum, off, 64);
            m_i[r] = mnew;
            l_i[r] = l_i[r] * alpha + sum;
#pragma unroll
            for (int ni = 0; ni < 4; ++ni) o_acc[ni][r] *= alpha;
        }

        // ---- P -> LDS (bf16, wave-private rows; swizzled like Qs/Ks) ----
#pragma unroll
        for (int r = 0; r < 4; ++r) {
            const int qr = w * 16 + 4 * lg + r;
#pragma unroll
            for (int ni = 0; ni < 4; ++ni) {
                const int kvc = 16 * ni + lf;
                Ps[qr * 64 + (((kvc >> 3) ^ (qr & 7)) << 3) + (kvc & 7)] =
                    f2bf(st[ni][r]);
            }
        }
        asm volatile("s_waitcnt lgkmcnt(0)" ::: "memory");
        __builtin_amdgcn_sched_barrier(0);

        // ---- O += P . V  (B = Vt[d][kv]) ----
#pragma unroll
        for (int ks = 0; ks < 2; ++ks) {
            bf16x8 pa = *reinterpret_cast<const bf16x8*>(
                &Ps[arow * 64 + (((ks * 4 + lg) ^ (arow & 7)) << 3)]);
#pragma unroll
            for (int ni = 0; ni < 4; ++ni) {
                const int drow = ni * 16 + lf;
                bf16x8 vb = *reinterpret_cast<const bf16x8*>(
                    &Vt[drow * 64 + (((ks * 4 + lg) ^ (drow & 7)) << 3)]);
                o_acc[ni] = __builtin_amdgcn_mfma_f32_16x16x32_bf16(pa, vb, o_acc[ni], 0, 0, 0);
            }
        }
        __syncthreads();   // all reads of Ks/Vt done before next-tile staging
    }

    // ---- write O (bf16) ----
#pragma unroll
    for (int r = 0; r < 4; ++r) {
        const float invl = 1.0f / l_i[r];
        const int qrow = w * 16 + 4 * lg + r;
#pragma unroll
        for (int ni = 0; ni < 4; ++ni)
            o[qbase + (size_t)qrow * QN + 16 * ni + lf] =
                f2bf(o_acc[ni][r] * invl);
    }
}

// ---------------- residual add + layernorm (in place on h; emits bf16 copy) ---
__global__ __launch_bounds__(256) void add_ln_kernel(
        float* __restrict__ h, const float* __restrict__ delta,
        const float* __restrict__ sc, const float* __restrict__ bi,
        ushort* __restrict__ hb) {
    const int t = blockIdx.x;
    const int d = threadIdx.x;
    __shared__ float p1[4], p2[4];
    const size_t idx = (size_t)t * DD + d;
    float val = h[idx] + delta[idx];
    float s = val;
#pragma unroll
    for (int off = 1; off < 64; off <<= 1) s += __shfl_xor(s, off, 64);
    if ((d & 63) == 0) p1[d >> 6] = s;
    __syncthreads();
    float mean = (p1[0] + p1[1] + p1[2] + p1[3]) * (1.0f / DD);
    float dv = val - mean;
    float vs = dv * dv;
#pragma unroll
    for (int off = 1; off < 64; off <<= 1) vs += __shfl_xor(vs, off, 64);
    if ((d & 63) == 0) p2[d >> 6] = vs;
    __syncthreads();
    float inv = rsqrtf((p2[0] + p2[1] + p2[2] + p2[3]) * (1.0f / DD) + 1e-5f);
    float r = dv * inv * sc[d] + bi[d];
    h[idx] = r;
    hb[idx] = f2bf(r);
}

// ---------------- launch ----------------
extern "C" void kernel_launch(void* const* d_in, const int* in_sizes, int n_in,
                              void* d_out, int out_size, void* d_ws, size_t ws_size,
                              hipStream_t stream) {
    (void)in_sizes; (void)n_in; (void)out_size; (void)ws_size;

    const int*   x    = (const int*)d_in[0];
    const float* emb  = (const float*)d_in[1];
    const float* wq   = (const float*)d_in[2];
    const float* bq   = (const float*)d_in[3];
    const float* wk   = (const float*)d_in[4];
    const float* bk   = (const float*)d_in[5];
    const float* wv   = (const float*)d_in[6];
    const float* bv   = (const float*)d_in[7];
    const float* wo   = (const float*)d_in[8];
    const float* bo   = (const float*)d_in[9];
    const float* ln1s = (const float*)d_in[10];
    const float* ln1b = (const float*)d_in[11];
    const float* w1   = (const float*)d_in[12];
    const float* b1   = (const float*)d_in[13];
    const float* w2   = (const float*)d_in[14];
    const float* b2   = (const float*)d_in[15];
    const float* ln2s = (const float*)d_in[16];
    const float* ln2b = (const float*)d_in[17];
    const float* ow   = (const float*)d_in[18];
    const float* ob   = (const float*)d_in[19];

    // workspace layout (~101 MB)
    char* ws = (char*)d_ws;
    float*  h   = (float*)ws;   ws += (size_t)BS * DD * 4;
    ushort* hbf = (ushort*)ws;  ws += (size_t)BS * DD * 2;
    ushort* qb  = (ushort*)ws;  ws += (size_t)BS * QN * 2;
    ushort* kb  = (ushort*)ws;  ws += (size_t)BS * QN * 2;
    ushort* vb  = (ushort*)ws;  ws += (size_t)BS * QN * 2;
    float*  t2  = (float*)ws;   ws += (size_t)BS * DD * 4;
    ushort* wqt = (ushort*)ws;  ws += (size_t)NLAYER * QN * DD * 2;
    ushort* wkt = (ushort*)ws;  ws += (size_t)NLAYER * QN * DD * 2;
    ushort* wvt = (ushort*)ws;  ws += (size_t)NLAYER * QN * DD * 2;
    ushort* wot = (ushort*)ws;  ws += (size_t)NLAYER * DD * QN * 2;
    ushort* w1t = (ushort*)ws;  ws += (size_t)NLAYER * FFD * DD * 2;
    ushort* w2t = (ushort*)ws;  ws += (size_t)NLAYER * DD * FFD * 2;
    ushort* owt = (ushort*)ws;  ws += (size_t)OUTD * DD * 2;
    ushort* ao  = qb;           // attention out aliases q
    ushort* ffh = kb;           // FFN hidden aliases k+v

    for (int i = 0; i < NLAYER; ++i) {
        convw_kernel<<<dim3(QN / 32, DD / 32), 256, 0, stream>>>(
            wq + (size_t)i * DD * QN, wqt + (size_t)i * QN * DD, DD, QN);
        convw_kernel<<<dim3(QN / 32, DD / 32), 256, 0, stream>>>(
            wk + (size_t)i * DD * QN, wkt + (size_t)i * QN * DD, DD, QN);
        convw_kernel<<<dim3(QN / 32, DD / 32), 256, 0, stream>>>(
            wv + (size_t)i * DD * QN, wvt + (size_t)i * QN * DD, DD, QN);
        convw_kernel<<<dim3(DD / 32, QN / 32), 256, 0, stream>>>(
            wo + (size_t)i * QN * DD, wot + (size_t)i * DD * QN, QN, DD);
        convw_kernel<<<dim3(FFD / 32, DD / 32), 256, 0, stream>>>(
            w1 + (size_t)i * DD * FFD, w1t + (size_t)i * FFD * DD, DD, FFD);
        convw_kernel<<<dim3(DD / 32, FFD / 32), 256, 0, stream>>>(
            w2 + (size_t)i * FFD * DD, w2t + (size_t)i * DD * FFD, FFD, DD);
    }
    convw_kernel<<<dim3(OUTD / 32, DD / 32), 256, 0, stream>>>(ow, owt, DD, OUTD);

    embed_pe_kernel<<<BS, 256, 0, stream>>>(x, emb, h, hbf);

    for (int i = 0; i < NLAYER; ++i) {
        dim3 gq(QN / 128, BS / 128);
        gemm_mfma_kernel<false, true><<<gq, 256, 0, stream>>>(
            hbf, wqt + (size_t)i * QN * DD, bq + i * QN, qb, BS, QN, DD);
        gemm_mfma_kernel<false, true><<<gq, 256, 0, stream>>>(
            hbf, wkt + (size_t)i * QN * DD, bk + i * QN, kb, BS, QN, DD);
        gemm_mfma_kernel<false, true><<<gq, 256, 0, stream>>>(
            hbf, wvt + (size_t)i * QN * DD, bv + i * QN, vb, BS, QN, DD);

        flash_attn_kernel<<<dim3(SS / 64, HH, BB), 256, 0, stream>>>(qb, kb, vb, ao);

        gemm_mfma_kernel<false, false><<<dim3(DD / 128, BS / 128), 256, 0, stream>>>(
            ao, wot + (size_t)i * DD * QN, bo + i * DD, t2, BS, DD, QN);
        add_ln_kernel<<<BS, 256, 0, stream>>>(h, t2, ln1s + i * DD, ln1b + i * DD, hbf);

        gemm_mfma_kernel<true, true><<<dim3(FFD / 128, BS / 128), 256, 0, stream>>>(
            hbf, w1t + (size_t)i * FFD * DD, b1 + i * FFD, ffh, BS, FFD, DD);
        gemm_mfma_kernel<false, false><<<dim3(DD / 128, BS / 128), 256, 0, stream>>>(
            ffh, w2t + (size_t)i * DD * FFD, b2 + i * DD, t2, BS, DD, FFD);
        add_ln_kernel<<<BS, 256, 0, stream>>>(h, t2, ln2s + i * DD, ln2b + i * DD, hbf);
    }

    gemm_mfma_kernel<false, false><<<dim3(OUTD / 128, BS / 128), 256, 0, stream>>>(
        hbf, owt, ob, (float*)d_out, BS, OUTD, DD);
}